// Round 5
// baseline (286.513 us; speedup 1.0000x reference)
//
#include <hip/hip_runtime.h>

typedef float f32x4  __attribute__((ext_vector_type(4)));
typedef float f32x16 __attribute__((ext_vector_type(16)));
typedef short s16x8  __attribute__((ext_vector_type(8)));

constexpr int NL  = 31;
constexpr int BB  = 64;
constexpr int TT  = 512;
constexpr int DD  = 768;
constexpr int RTOT = BB * TT;
constexpr int IDX_EOS = 29;
constexpr int IDX_BOS = 30;
constexpr float LOG2E = 1.4426950408889634f;
constexpr float LN2F  = 0.6931471805599453f;

union Frag8 { unsigned u[4]; s16x8 s; };

__device__ inline unsigned pk2(float a, float b) {
  unsigned ua = __float_as_uint(a), ub = __float_as_uint(b);
  ua = (ua + 0x7fffu + ((ua >> 16) & 1u)) >> 16;   // RNE f32->bf16
  ub = (ub + 0x7fffu + ((ub >> 16) & 1u)) >> 16;
  return ua | (ub << 16);
}
__device__ inline unsigned short bf16r(float a) {
  unsigned ua = __float_as_uint(a);
  return (unsigned short)((ua + 0x7fffu + ((ua >> 16) & 1u)) >> 16);
}

__device__ inline float bfly_max32(float v) {
#define STEPM(K) { float o = __int_as_float(__builtin_amdgcn_ds_swizzle(__float_as_int(v), ((K) << 10) | 0x1f)); v = fmaxf(v, o); }
  STEPM(1) STEPM(2) STEPM(4) STEPM(8) STEPM(16)
#undef STEPM
  return v;
}
__device__ inline float bfly_sum32(float v) {
#define STEPS(K) { float o = __int_as_float(__builtin_amdgcn_ds_swizzle(__float_as_int(v), ((K) << 10) | 0x1f)); v = v + o; }
  STEPS(1) STEPS(2) STEPS(4) STEPS(8) STEPS(16)
#undef STEPS
  return v;
}

// D(C-layout, f32[16]) -> B-frag(bf16) half-swap repack [R2-verified]
__device__ inline void repack(const float E[16], int h, Frag8& B1, Frag8& B2) {
  unsigned o1a = pk2(E[4 * h], E[4 * h + 1]), o1b = pk2(E[4 * h + 2], E[4 * h + 3]);
  unsigned o2a = pk2(E[8 + 4 * h], E[8 + 4 * h + 1]), o2b = pk2(E[8 + 4 * h + 2], E[8 + 4 * h + 3]);
  int hb = 4 * (1 - h);
  unsigned s1a = pk2(E[hb], E[hb + 1]),         s1b = pk2(E[hb + 2], E[hb + 3]);
  unsigned s2a = pk2(E[8 + hb], E[8 + hb + 1]), s2b = pk2(E[8 + hb + 2], E[8 + hb + 3]);
  unsigned r1a = __shfl_xor((int)s1a, 32), r1b = __shfl_xor((int)s1b, 32);
  unsigned r2a = __shfl_xor((int)s2a, 32), r2b = __shfl_xor((int)s2b, 32);
  if (h == 0) {
    B1.u[0] = o1a; B1.u[1] = o1b; B1.u[2] = r1a; B1.u[3] = r1b;
    B2.u[0] = o2a; B2.u[1] = o2b; B2.u[2] = r2a; B2.u[3] = r2b;
  } else {
    B1.u[0] = r1a; B1.u[1] = r1b; B1.u[2] = o1a; B1.u[3] = o1b;
    B2.u[0] = r2a; B2.u[1] = r2b; B2.u[2] = o2a; B2.u[3] = o2b;
  }
}

__device__ inline void renorm16(float E[16], float& Sacc) {
  float m = E[0];
#pragma unroll
  for (int r = 1; r < 16; ++r) m = fmaxf(m, E[r]);
  m = bfly_max32(m);
  m = fmaxf(m, __shfl_xor(m, 32));
  float lg = truncf(log2f(m));
  Sacc += lg;
  float sc = exp2f(-lg);
#pragma unroll
  for (int r = 0; r < 16; ++r) E[r] *= sc;
}

// bf16 row-major 32x32 matrix -> A-frags (A[m][k], m = lane&31)
__device__ inline void load_A16(const unsigned short* M, int l, int h, Frag8& A1, Frag8& A2) {
  A1.s = *(const s16x8*)(M + l * 32 + 8 * h);
  A2.s = *(const s16x8*)(M + l * 32 + 16 + 8 * h);
}
// bf16 row-major 32x32 matrix -> B-frags (B[k][n], n = lane&31)
__device__ inline void load_B16(const unsigned short* M, int l, int h, Frag8& B1, Frag8& B2) {
#pragma unroll
  for (int m = 0; m < 4; ++m) {
    int k = 8 * h + 2 * m;
    unsigned lo0 = M[k * 32 + l],        hi0 = M[(k + 1) * 32 + l];
    unsigned lo1 = M[(k + 16) * 32 + l], hi1 = M[(k + 17) * 32 + l];
    B1.u[m] = lo0 | (hi0 << 16);
    B2.u[m] = lo1 | (hi1 << 16);
  }
}

// LDS tree node: result = T[ja] * T[jb] -> stored at T[jb] (bf16), Ts[jb] += S
// (ja = LATER segment, jb = EARLIER segment)  [R2-verified]
__device__ inline void tree_node(unsigned short* Tb, float* Ts, int ja, int jb, int l, int h) {
  Frag8 A1, A2, B1, B2;
  load_A16(Tb + ja * 1024, l, h, A1, A2);
  load_B16(Tb + jb * 1024, l, h, B1, B2);
  f32x16 D = {};
  D = __builtin_amdgcn_mfma_f32_32x32x16_bf16(A1.s, B1.s, D, 0, 0, 0);
  D = __builtin_amdgcn_mfma_f32_32x32x16_bf16(A2.s, B2.s, D, 0, 0, 0);
  float E[16];
#pragma unroll
  for (int r = 0; r < 16; ++r) E[r] = D[r];
  float S = Ts[ja] + Ts[jb];
  renorm16(E, S);
#pragma unroll
  for (int r = 0; r < 16; ++r) {
    int row = (r & 3) + 8 * (r >> 2) + 4 * h;
    Tb[jb * 1024 + row * 32 + l] = bf16r(E[r]);
  }
  if (l == 0 && h == 0) Ts[jb] = S;
}

// ------------- K0: state_w -> bf16 padded ----------------------------------
__global__ void k_prep(const float* __restrict__ sw, unsigned short* __restrict__ Bw) {
  for (int i = blockIdx.x * 256 + threadIdx.x; i < 32 * DD; i += 8 * 256)
    Bw[i] = (i < NL * DD) ? bf16r(sw[i]) : (unsigned short)0;
}

// ------------- K1 fused: GEMM + energy + tgt partial + seg chain ------------
// 2048 blocks x 16 rows. __launch_bounds__(256,8) pins total regs <=64 so 8
// blocks/CU stay resident (R4 post-mortem: f32x16 pushed regs past 64 ->
// 4 waves/SIMD -> x1.7 duration).
// Phase A: wave 0 = direct-load GEMM -> osh; waves 1-3 = trans -> LDS.
// Phase B (concurrent): wave 0 = 16-step CRF segment chain -> Mb/Sb;
//                       waves 1-3 = energy store stream + tgt partial.
__global__ __launch_bounds__(256, 8) void k_fused(
    const float* __restrict__ inp, const unsigned short* __restrict__ Bw,
    const float* __restrict__ sb, const float* __restrict__ msk,
    const float* __restrict__ trans, const int* __restrict__ target,
    float* __restrict__ energy, float* __restrict__ ws_partial,
    unsigned short* __restrict__ Mb, float* __restrict__ Sb,
    float* __restrict__ out0)
{
  __shared__ float tr[961];
  __shared__ float osh[16 * NL];
  int tid = threadIdx.x, wave = tid >> 6, lane = tid & 63;
  int bid = blockIdx.x;
  int r0 = bid * 16;

  if (wave) {
    // waves 1-3: trans -> LDS while wave 0 runs the GEMM
    for (int idx = tid - 64; idx < 961; idx += 192) tr[idx] = trans[idx];
  } else {
    // ---- wave 0: 16-row GEMM, direct per-lane A-fragment loads ----
    int quad = lane >> 4, l15 = lane & 15;
    const float* arow = inp + (size_t)(r0 + l15) * DD + quad * 8;

    f32x4 pa0a = *(const f32x4*)(arow);
    f32x4 pa0b = *(const f32x4*)(arow + 4);
    f32x4 pa1a = *(const f32x4*)(arow + 32);
    f32x4 pa1b = *(const f32x4*)(arow + 36);

    f32x4 acc[2] = {};
    for (int kc = 0; kc < 12; ++kc) {
      Frag8 af0, af1;
      af0.u[0] = pk2(pa0a[0], pa0a[1]); af0.u[1] = pk2(pa0a[2], pa0a[3]);
      af0.u[2] = pk2(pa0b[0], pa0b[1]); af0.u[3] = pk2(pa0b[2], pa0b[3]);
      af1.u[0] = pk2(pa1a[0], pa1a[1]); af1.u[1] = pk2(pa1a[2], pa1a[3]);
      af1.u[2] = pk2(pa1b[0], pa1b[1]); af1.u[3] = pk2(pa1b[2], pa1b[3]);
      if (kc < 11) {
        const float* a2 = arow + (kc + 1) * 64;
        pa0a = *(const f32x4*)(a2);      pa0b = *(const f32x4*)(a2 + 4);
        pa1a = *(const f32x4*)(a2 + 32); pa1b = *(const f32x4*)(a2 + 36);
      }
#pragma unroll
      for (int ct = 0; ct < 2; ++ct) {
        s16x8 bf0 = *(const s16x8*)(Bw + (ct * 16 + l15) * DD + kc * 64 + quad * 8);
        acc[ct] = __builtin_amdgcn_mfma_f32_16x16x32_bf16(af0.s, bf0, acc[ct], 0, 0, 0);
        s16x8 bf1 = *(const s16x8*)(Bw + (ct * 16 + l15) * DD + kc * 64 + 32 + quad * 8);
        acc[ct] = __builtin_amdgcn_mfma_f32_16x16x32_bf16(af1.s, bf1, acc[ct], 0, 0, 0);
      }
    }
    // epilogue: bias + mask -> osh
#pragma unroll
    for (int ct = 0; ct < 2; ++ct) {
      int n = ct * 16 + l15;
      if (n < NL) {
        float b = sb[n];
#pragma unroll
        for (int r = 0; r < 4; ++r) {
          int lr = quad * 4 + r;
          float v = acc[ct][r] + b;
          if (n == IDX_EOS && msk[r0 + lr] == 0.f) v += 20000.f;
          osh[lr * NL + n] = v;
        }
      }
    }
  }
  __syncthreads();

  // batch-first block (k==0): save row 0 of outs for the final p0
  if ((bid & 31) == 0 && tid < NL) out0[(bid >> 5) * NL + tid] = osh[tid];

  if (wave == 0) {
    // ============ wave 0: 16-step CRF segment chain (concurrent w/ stores) ==
    int l = lane & 31, h = lane >> 5;
    int s0 = ((bid & 31) == 0) ? 1 : 0;   // t=0 is the start dist, not a step

    Frag8 A1, A2, B1, B2;
#pragma unroll
    for (int m = 0; m < 4; ++m) {
      int k0 = 8 * h + 2 * m, k1 = k0 + 1;
      float a0 = (k0 < NL && l < NL) ? exp2f(LOG2E * tr[k0 * NL + l]) : 0.f;
      float a1 = (k1 < NL && l < NL) ? exp2f(LOG2E * tr[k1 * NL + l]) : 0.f;
      A1.u[m] = pk2(a0, a1);
      int k2 = 16 + k0, k3 = 16 + k1;
      float a2 = (k2 < NL && l < NL) ? exp2f(LOG2E * tr[k2 * NL + l]) : 0.f;
      float a3 = (k3 < NL && l < NL) ? exp2f(LOG2E * tr[k3 * NL + l]) : 0.f;
      A2.u[m] = pk2(a2, a3);
      B1.u[m] = ((k0 == l) ? 0x3f80u : 0u) | (((k1 == l) ? 0x3f80u : 0u) << 16);
      B2.u[m] = ((k2 == l) ? 0x3f80u : 0u) | (((k3 == l) ? 0x3f80u : 0u) << 16);
    }

    float E[16];
    float S = 0.f;
    for (int s = s0; s < 16; ++s) {
      f32x16 D = {};
      D = __builtin_amdgcn_mfma_f32_32x32x16_bf16(A1.s, B1.s, D, 0, 0, 0);
      D = __builtin_amdgcn_mfma_f32_32x32x16_bf16(A2.s, B2.s, D, 0, 0, 0);
#pragma unroll
      for (int t = 0; t < 4; ++t) {
#pragma unroll
        for (int jj = 0; jj < 4; ++jj) {
          int col = t * 8 + 4 * h + jj;
          float u = (col < NL) ? exp2f(LOG2E * osh[s * NL + col]) : 0.f;
          E[4 * t + jj] = D[4 * t + jj] * u;
        }
      }
      if ((s & 3) == 3) renorm16(E, S);   // every 4 steps incl. s=15
      if (s < 15) repack(E, h, B1, B2);
    }
    unsigned short* mo = Mb + (size_t)bid * 1024;
#pragma unroll
    for (int r = 0; r < 16; ++r) {
      int row = (r & 3) + 8 * (r >> 2) + 4 * h;
      mo[row * 32 + l] = bf16r(E[r]);
    }
    if (lane == 0) Sb[bid] = S;
  } else {
    // ============ waves 1-3: tgt partial + energy store stream ==============
    if (wave == 1 && lane < 16) {
      int r = r0 + lane;
      int tg = target[r];
      int prv = ((r & (TT - 1)) == 0) ? IDX_BOS : target[r - 1];
      float cc = tr[prv * NL + tg] + osh[lane * NL + tg];
#pragma unroll
      for (int off = 8; off; off >>= 1) cc += __shfl_down(cc, off);
      if (lane == 0) ws_partial[bid] = cc;
    }

    // energy: 16*961 = 15376 f32 = 3844 vec4. 192 threads x 20 + 4 tail.
    // Incremental indices (961 = 31*31): e%31 advances +1 mod 31 across the
    // %961 wrap, so no divisions in the loop.
    float* dst = energy + (size_t)r0 * 961;
    int v0 = tid - 64;                       // 0..191
    unsigned c = (unsigned)(v0 * 4);         // e % 961  (e = v0*4 < 961)
    unsigned j = c - 31u * ((c * 67651u) >> 21); // e % 31
    unsigned oq = j;                         // (e/961)*31 + j, q=0 initially
    for (int it = 0; it < 20; ++it) {
      unsigned cc = c, jj = j, qq = oq;
      f32x4 val;
#pragma unroll
      for (int k = 0; k < 4; ++k) {
        val[k] = tr[cc] + osh[qq];
        ++cc; ++jj; ++qq;
        if (jj == 31u) { jj = 0u; qq -= 31u; }
        if (cc == 961u) { cc = 0u; qq += 31u; }
      }
      *(f32x4*)(dst + it * 768 + v0 * 4) = val;
      // advance start state by +768 elements
      c += 768u; j += 24u; oq += 24u;
      if (j >= 31u) { j -= 31u; oq -= 31u; }
      if (c >= 961u) { c -= 961u; oq += 31u; }
    }
    if (v0 < 4) {
      int e = (3840 + v0) * 4;
      f32x4 val;
#pragma unroll
      for (int k = 0; k < 4; ++k) {
        unsigned x = e + k;
        unsigned q = __umulhi(x, 4469269u);        // x / 961
        unsigned cx = x - q * 961u;
        unsigned jx = cx - 31u * ((cx * 67651u) >> 21);
        val[k] = tr[cx] + osh[q * NL + jx];
      }
      *(f32x4*)(dst + e) = val;
    }
  }
}

// ------------- K2: per-batch depth-5 tree over 32 segment matrices + loss ---
__global__ __launch_bounds__(256) void k_tree(
    const float* __restrict__ trans, const unsigned short* __restrict__ Mb,
    const float* __restrict__ Sb, const float* __restrict__ ws_partial,
    const float* __restrict__ out0, float* __restrict__ loss)
{
  __shared__ __align__(16) unsigned short T[32][1024];
  __shared__ float Ts[32];
  __shared__ float wsh[32];
  int tid = threadIdx.x, wave = tid >> 6, lane = tid & 63;
  int l = lane & 31, h = lane >> 5;
  int b = blockIdx.x;

  const f32x4* src = (const f32x4*)(Mb + (size_t)b * 32 * 1024);
  f32x4* dstT = (f32x4*)T;
#pragma unroll
  for (int i = 0; i < 16; ++i) dstT[tid + i * 256] = src[tid + i * 256];
  if (tid < 32) {
    Ts[tid] = Sb[b * 32 + tid];
    wsh[tid] = ws_partial[b * 32 + tid];
  }
  __syncthreads();

  unsigned short* T0 = T[0];
  // L1 (32->16): node(2j+1, 2j)
#pragma unroll
  for (int i = 0; i < 4; ++i) { int j = wave + 4 * i; tree_node(T0, Ts, 2 * j + 1, 2 * j, l, h); }
  __syncthreads();
  // L2 (16->8): node(4j+2, 4j)
#pragma unroll
  for (int i = 0; i < 2; ++i) { int j = wave + 4 * i; tree_node(T0, Ts, 4 * j + 2, 4 * j, l, h); }
  __syncthreads();
  // L3 (8->4): node(8j+4, 8j)
  { int j = wave; tree_node(T0, Ts, 8 * j + 4, 8 * j, l, h); }
  __syncthreads();
  // L4 (4->2): node(16j+8, 16j)
  if (wave < 2) { int j = wave; tree_node(T0, Ts, 16 * j + 8, 16 * j, l, h); }
  __syncthreads();

  // L5 + finalize (wave 0): full = T[16] * T[0]
  if (wave == 0) {
    Frag8 A1, A2, B1, B2;
    load_A16(T0 + 16 * 1024, l, h, A1, A2);
    load_B16(T0, l, h, B1, B2);
    f32x16 D = {};
    D = __builtin_amdgcn_mfma_f32_32x32x16_bf16(A1.s, B1.s, D, 0, 0, 0);
    D = __builtin_amdgcn_mfma_f32_32x32x16_bf16(A2.s, B2.s, D, 0, 0, 0);
    float E[16];
#pragma unroll
    for (int r = 0; r < 16; ++r) E[r] = D[r];
    float S = Ts[0] + Ts[16];

    float p0 = (l < NL) ? exp2f(LOG2E * (trans[IDX_BOS * NL + l] + out0[b * NL + l])) : 0.f;
    float sum_h = 0.f;
#pragma unroll
    for (int r = 0; r < 16; ++r) {
      float s = bfly_sum32(E[r] * p0);
      int row = (r & 3) + 8 * (r >> 2) + 4 * h;
      float We = (row < NL) ? exp2f(LOG2E * trans[row * NL + IDX_EOS]) : 0.f;
      sum_h += s * We;
    }
    float tot = sum_h + __shfl_xor(sum_h, 32);
    if (lane == 0) {
      float wst = 0.f;
#pragma unroll
      for (int i = 0; i < 32; ++i) wst += wsh[i];
      loss[b] = LN2F * (S + log2f(tot)) - wst;
    }
  }
}

extern "C" void kernel_launch(void* const* d_in, const int* in_sizes, int n_in,
                              void* d_out, int out_size, void* d_ws, size_t ws_size,
                              hipStream_t stream) {
  const float* inp   = (const float*)d_in[0];   // (64,512,768) f32
  const int*   tgt   = (const int*)d_in[1];     // (64,512) int
  const float* msk   = (const float*)d_in[2];   // (64,512) f32
  const float* sw    = (const float*)d_in[3];   // (31,768) f32
  const float* sb    = (const float*)d_in[4];   // (31,) f32
  const float* trans = (const float*)d_in[5];   // (31,31) f32

  float* out    = (float*)d_out;
  float* loss   = out;
  float* energy = out + BB;

  // d_ws layout (~4.2 MB used)
  float* ws_partial = (float*)d_ws;                    // 2048
  float* Sb   = ws_partial + 2048;                     // 2048
  float* out0 = Sb + 2048;                             // 64*31 -> pad 2048
  unsigned short* Mb = (unsigned short*)(out0 + 2048); // 2048*1024 bf16
  unsigned short* Bw = Mb + (size_t)2048 * 1024;       // 32*768 bf16

  k_prep<<<8, 256, 0, stream>>>(sw, Bw);
  k_fused<<<RTOT / 16, 256, 0, stream>>>(inp, Bw, sb, msk, trans, tgt,
                                         energy, ws_partial, Mb, Sb, out0);
  k_tree<<<BB, 256, 0, stream>>>(trans, Mb, Sb, ws_partial, out0, loss);
}